// Round 6
// baseline (563.459 us; speedup 1.0000x reference)
//
#include <hip/hip_runtime.h>
#include <hip/hip_bf16.h>

typedef unsigned short u16;
typedef __bf16 bf16x8 __attribute__((ext_vector_type(8)));
typedef float f32x4 __attribute__((ext_vector_type(4)));

// B=8, S=4096 (spatial), C=512 (channels). per-batch embed elems = 2097152.
// packA (per batch-group): [nb][3 scales][sgb 256][cb 16][lane 64][e 8] bf16
//   fragment def: packA[lb][sc][sgb][cb][l][e] = pooled[c=cb*32+(l>>4)*8+e][s=sgb*16+(l&15)]

static __device__ __forceinline__ u16 f2bf(float f) {
  unsigned u = __builtin_bit_cast(unsigned, f);
  unsigned r = (u + 0x7FFFu + ((u >> 16) & 1u)) >> 16;
  return (u16)r;
}

// ---------------- fused 3x3x3 avg-pool (/27, count_include_pad) + A-pack ----
__global__ __launch_bounds__(512) void k_poolpack(const float* __restrict__ e0,
                                                  const float* __restrict__ e1,
                                                  const float* __restrict__ e2,
                                                  u16* __restrict__ packA,
                                                  int b0, int nb) {
  __shared__ __align__(16) float v[4096];
  __shared__ __align__(16) float t1[4096];
  __shared__ __align__(16) u16 outp[16384];   // [s][ci 0..3]
  int bx = blockIdx.x;
  int cg4 = bx & 127;
  int q = bx >> 7;
  int scale = q / nb;
  int lb = q - scale * nb;
  int b = b0 + lb;
  const float* eptr = scale == 0 ? e0 : (scale == 1 ? e1 : e2);
  const int LW = (scale == 0) ? 4 : (scale == 1 ? 3 : 4);
  const int LHW = (scale == 0) ? 8 : (scale == 1 ? 7 : 9);
  const int w = 1 << LW, hw = 1 << LHW;
  const int h = hw >> LW;
  const int dep = 4096 >> LHW;
  int t = threadIdx.x;
  int c0 = cg4 * 4;
  for (int ci = 0; ci < 4; ++ci) {
    const float* src = eptr + (size_t)b * 2097152 + (size_t)(c0 + ci) * 4096;
    ((float4*)v)[t] = ((const float4*)src)[t];
    ((float4*)v)[t + 512] = ((const float4*)src)[t + 512];
    __syncthreads();
    for (int j = 0; j < 8; ++j) {          // x pass
      int s = t + j * 512;
      int x = s & (w - 1);
      float sum = v[s];
      if (x > 0) sum += v[s - 1];
      if (x < w - 1) sum += v[s + 1];
      t1[s] = sum;
    }
    __syncthreads();
    for (int j = 0; j < 8; ++j) {          // y pass
      int s = t + j * 512;
      int y = (s >> LW) & (h - 1);
      float sum = t1[s];
      if (y > 0) sum += t1[s - w];
      if (y < h - 1) sum += t1[s + w];
      v[s] = sum;
    }
    __syncthreads();
    for (int j = 0; j < 8; ++j) {          // z pass -> bf16
      int s = t + j * 512;
      int z = s >> LHW;
      float sum = v[s];
      if (z > 0) sum += v[s - hw];
      if (z < dep - 1) sum += v[s + hw];
      outp[s * 4 + ci] = f2bf(sum * (1.0f / 27.0f));
    }
    __syncthreads();
  }
  int cb = c0 >> 5;
  int hi = (c0 >> 3) & 3;
  int eh = (c0 >> 2) & 1;
  size_t blk = (size_t)(lb * 3 + scale) * 2097152;
  for (int k2 = 0; k2 < 8; ++k2) {
    int s = t + k2 * 512;
    int2 val = *(const int2*)&outp[s * 4];
    size_t dst = blk + ((size_t)(s >> 4) * 16 + cb) * 512 +
                 (size_t)(hi * 16 + (s & 15)) * 8 + eh * 4;
    *(int2*)(packA + dst) = val;
  }
}

// ---------------- pack W1 into MFMA B-fragment layout -----------------------
// W1p[(kp*32+nb)*32+kb][l][e] = W1[kp][kb*32 + (l>>4)*8 + e][nb*16 + (l&15)]
__global__ __launch_bounds__(64) void k_packW(const float* __restrict__ W1,
                                              u16* __restrict__ W1p) {
  int u = blockIdx.x;
  int kb = u & 31;
  int nb_ = (u >> 5) & 31;
  int kp = u >> 10;
  int l = threadIdx.x;
  int m = l & 15, hi = l >> 4;
  u16 tmp[8];
  for (int e = 0; e < 8; ++e) {
    int kg = kb * 32 + hi * 8 + e;
    tmp[e] = f2bf(W1[((size_t)kp * 1024 + kg) * 512 + nb_ * 16 + m]);
  }
  *(int4*)(W1p + ((size_t)u * 64 + l) * 8) = *(int4*)tmp;
}

// ---------------- fused GEMM + bias + relu + dot(W2) -> logits --------------
// A staged in LDS via async global_load_lds (4 chunks of 32 KiB, double-buffered,
// counted vmcnt(4) so next chunk's loads stay in flight across barriers).
// B (W1p, 3 MiB) stays in global -> L2-resident.
__global__ __launch_bounds__(512) void k_gemm(const u16* __restrict__ packA,
                                              const u16* __restrict__ W1p,
                                              const float* __restrict__ b1,
                                              const float* __restrict__ W2,
                                              float* __restrict__ logits,
                                              int b0, int nb) {
  __shared__ __align__(16) u16 abuf[2][16384];  // 2 x 32 KiB A chunks
  __shared__ float red[512];
  int per = gridDim.x >> 3;                 // grid = 384*nb, always %8==0
  int logical = (blockIdx.x & 7) * per + (blockIdx.x >> 3);
  int dir = logical % 6;
  int group = logical / 6;
  int mt = group & 63;
  int lb = group >> 6;
  int b = b0 + lb;
  int kp = dir >> 1, sw = dir & 1;
  const int PI[3] = {0, 0, 1}, PJ[3] = {1, 2, 2};
  int pi = PI[kp], pj = PJ[kp];
  int first = sw ? pj : pi;
  int second = sw ? pi : pj;
  int t = threadIdx.x;
  int w = t >> 6;
  int l = t & 63;
  // panel bases WITHOUT lane offset (staging adds l*8 itself)
  const u16* Abase1 = packA + (size_t)(lb * 3 + first) * 2097152 + (size_t)mt * 32768;
  const u16* Abase2 = packA + (size_t)(lb * 3 + second) * 2097152 + (size_t)mt * 32768;
  const u16* Bp = W1p + ((size_t)kp * 32 + w * 4) * 32 * 512 + (size_t)l * 8;

  f32x4 acc[4][4];
  for (int a = 0; a < 4; ++a)
    for (int n = 0; n < 4; ++n) acc[a][n] = (f32x4){0.f, 0.f, 0.f, 0.f};

  // chunk c: panel = (c<2 ? Abase1 : Abase2), cb range = (c&1)*8 .. +8
  // LDS layout: abuf[buf][q*512 + lane*8], q = sgb*8 + cbi  (q = w*4+qi per wave)
#define STAGE(BUFI, CHUNK)                                                        \
  do {                                                                            \
    const u16* P_ = ((CHUNK) < 2) ? Abase1 : Abase2;                              \
    const int cc0_ = ((CHUNK) & 1) * 8;                                           \
    for (int qi = 0; qi < 4; ++qi) {                                              \
      int q_ = w * 4 + qi;                                                        \
      const u16* g_ = P_ + (size_t)(q_ >> 3) * 8192 +                             \
                      (size_t)(cc0_ + (q_ & 7)) * 512 + (size_t)l * 8;            \
      u16* lp_ = &abuf[BUFI][q_ * 512];                                           \
      __builtin_amdgcn_global_load_lds(                                           \
          (const __attribute__((address_space(1))) void*)g_,                      \
          (__attribute__((address_space(3))) void*)lp_, 16, 0, 0);                \
    }                                                                             \
  } while (0)

#define COMPUTE(BUFI, CHUNK)                                                      \
  do {                                                                            \
    _Pragma("unroll")                                                             \
    for (int kk = 0; kk < 8; ++kk) {                                              \
      int ks_ = (CHUNK) * 8 + kk;                                                 \
      bf16x8 af[4], bfr[4];                                                       \
      for (int mi = 0; mi < 4; ++mi)                                              \
        af[mi] = *(const bf16x8*)&abuf[BUFI][(mi * 8 + kk) * 512 + l * 8];        \
      for (int ni = 0; ni < 4; ++ni)                                              \
        bfr[ni] = *(const bf16x8*)(Bp + (size_t)(ni * 32 + ks_) * 512);           \
      for (int mi = 0; mi < 4; ++mi)                                              \
        for (int ni = 0; ni < 4; ++ni)                                            \
          acc[mi][ni] = __builtin_amdgcn_mfma_f32_16x16x32_bf16(                  \
              af[mi], bfr[ni], acc[mi][ni], 0, 0, 0);                             \
    }                                                                             \
  } while (0)

  STAGE(0, 0);
  // t=0
  STAGE(1, 1);
  asm volatile("s_waitcnt vmcnt(4)" ::: "memory");
  __builtin_amdgcn_sched_barrier(0);
  __builtin_amdgcn_s_barrier();
  COMPUTE(0, 0);
  __builtin_amdgcn_s_barrier();
  // t=1
  STAGE(0, 2);
  asm volatile("s_waitcnt vmcnt(4)" ::: "memory");
  __builtin_amdgcn_sched_barrier(0);
  __builtin_amdgcn_s_barrier();
  COMPUTE(1, 1);
  __builtin_amdgcn_s_barrier();
  // t=2
  STAGE(1, 3);
  asm volatile("s_waitcnt vmcnt(4)" ::: "memory");
  __builtin_amdgcn_sched_barrier(0);
  __builtin_amdgcn_s_barrier();
  COMPUTE(0, 2);
  __builtin_amdgcn_s_barrier();
  // t=3 (last: nothing left to prefetch, full drain)
  asm volatile("s_waitcnt vmcnt(0)" ::: "memory");
  __builtin_amdgcn_sched_barrier(0);
  __builtin_amdgcn_s_barrier();
  COMPUTE(1, 3);
#undef STAGE
#undef COMPUTE

  int m = l & 15, hi = l >> 4;
  float w2v[4], b1v[4];
  for (int ni = 0; ni < 4; ++ni) {
    int n = w * 64 + ni * 16 + m;
    w2v[ni] = W2[kp * 512 + n];
    b1v[ni] = b1[kp * 512 + n];
  }
  float rs[4][4];
  for (int mi = 0; mi < 4; ++mi)
    for (int r = 0; r < 4; ++r) {
      float s = 0.f;
      for (int ni = 0; ni < 4; ++ni) {
        float h = acc[mi][ni][r] + b1v[ni];
        s += fmaxf(h, 0.f) * w2v[ni];
      }
      float vv = s;
      vv += __shfl_xor(vv, 1);
      vv += __shfl_xor(vv, 2);
      vv += __shfl_xor(vv, 4);
      vv += __shfl_xor(vv, 8);
      rs[mi][r] = vv;
    }
  if (m == 0) {
    for (int mi = 0; mi < 4; ++mi)
      for (int r = 0; r < 4; ++r)
        red[w * 64 + mi * 16 + hi * 4 + r] = rs[mi][r];
  }
  __syncthreads();
  if (t < 64) {
    float s = 0.f;
    for (int ww = 0; ww < 8; ++ww) s += red[ww * 64 + t];
    logits[((size_t)dir * 8 + b) * 4096 + mt * 64 + t] = s;
  }
}

// ---------------- softmax over N per (dir,b), in-place, NaN-scrubbing -------
__global__ __launch_bounds__(256) void k_softmax(float* __restrict__ logits) {
  __shared__ __align__(16) float buf[4096];
  __shared__ float wred[4];
  int row = blockIdx.x;
  float* p = logits + (size_t)row * 4096;
  int t = threadIdx.x;
  float lmax = -1e30f;
  for (int j = 0; j < 4; ++j) {
    float4 v = ((const float4*)p)[t + j * 256];
    v.x = fmaxf(fminf(v.x, 1e4f), -1e4f);
    v.y = fmaxf(fminf(v.y, 1e4f), -1e4f);
    v.z = fmaxf(fminf(v.z, 1e4f), -1e4f);
    v.w = fmaxf(fminf(v.w, 1e4f), -1e4f);
    ((float4*)buf)[t + j * 256] = v;
    lmax = fmaxf(lmax, fmaxf(fmaxf(v.x, v.y), fmaxf(v.z, v.w)));
  }
  for (int off = 1; off < 64; off <<= 1) lmax = fmaxf(lmax, __shfl_xor(lmax, off));
  if ((t & 63) == 0) wred[t >> 6] = lmax;
  __syncthreads();
  float gmax = fmaxf(fmaxf(wred[0], wred[1]), fmaxf(wred[2], wred[3]));
  __syncthreads();
  float lsum = 0.f;
  for (int j = 0; j < 16; ++j) {
    int s = t + j * 256;
    float ex = expf(buf[s] - gmax);
    buf[s] = ex;
    lsum += ex;
  }
  for (int off = 1; off < 64; off <<= 1) lsum += __shfl_xor(lsum, off);
  if ((t & 63) == 0) wred[t >> 6] = lsum;
  __syncthreads();
  float inv = 1.f / (wred[0] + wred[1] + wred[2] + wred[3]);
  for (int j = 0; j < 4; ++j) {
    int i4 = t + j * 256;
    float4 v = ((const float4*)buf)[i4];
    v.x *= inv; v.y *= inv; v.z *= inv; v.w *= inv;
    ((float4*)p)[i4] = v;
  }
}

__global__ void k_zero(float* __restrict__ p, int n) {
  int i = blockIdx.x * 256 + threadIdx.x;
  if (i < n) p[i] = 0.f;
}

// ---------------- weighted sums + embed sums -> fused accumulator -----------
__global__ __launch_bounds__(256) void k_matched(const float* __restrict__ e0,
                                                 const float* __restrict__ e1,
                                                 const float* __restrict__ e2,
                                                 const float* __restrict__ wts,
                                                 float* __restrict__ fused) {
  __shared__ float lw[384];
  int bx = blockIdx.x;
  int nc = bx & 63;
  int b = bx >> 6;
  int n0 = nc * 64;
  int t = threadIdx.x;
  for (int idx = t; idx < 384; idx += 256) {
    int dir = idx >> 6, nn = idx & 63;
    lw[idx] = wts[((size_t)dir * 8 + b) * 4096 + n0 + nn];
  }
  __syncthreads();
  size_t base = (size_t)b * 2097152 + (size_t)n0 * 512;
  const float2* p0 = (const float2*)(e0 + base) + t;
  const float2* p1 = (const float2*)(e1 + base) + t;
  const float2* p2 = (const float2*)(e2 + base) + t;
  float2 tot = {0.f, 0.f};
  float2 m0 = {0, 0}, m1 = {0, 0}, m2 = {0, 0}, m3 = {0, 0}, m4 = {0, 0}, m5 = {0, 0};
  for (int nn = 0; nn < 64; ++nn) {
    float2 v0 = p0[nn * 256];
    float2 v1 = p1[nn * 256];
    float2 v2 = p2[nn * 256];
    tot.x += v0.x + v1.x + v2.x;
    tot.y += v0.y + v1.y + v2.y;
    float w0 = lw[0 * 64 + nn], w1 = lw[1 * 64 + nn], w2 = lw[2 * 64 + nn];
    float w3 = lw[3 * 64 + nn], w4 = lw[4 * 64 + nn], w5 = lw[5 * 64 + nn];
    m0.x += w0 * v1.x; m0.y += w0 * v1.y;
    m1.x += w1 * v0.x; m1.y += w1 * v0.y;
    m2.x += w2 * v2.x; m2.y += w2 * v2.y;
    m3.x += w3 * v0.x; m3.y += w3 * v0.y;
    m4.x += w4 * v2.x; m4.y += w4 * v2.y;
    m5.x += w5 * v1.x; m5.y += w5 * v1.y;
  }
  float rx = tot.x + m0.x + m1.x + m2.x + m3.x + m4.x + m5.x;
  float ry = tot.y + m0.y + m1.y + m2.y + m3.y + m4.y + m5.y;
  atomicAdd(&fused[b * 512 + 2 * t], rx);
  atomicAdd(&fused[b * 512 + 2 * t + 1], ry);
}

// ---------------- mean-div, LN, final matmul --------------------------------
__global__ __launch_bounds__(512) void k_final(const float* __restrict__ fused,
                                               const float* __restrict__ gamma,
                                               const float* __restrict__ beta,
                                               const float* __restrict__ Wf,
                                               const float* __restrict__ bfv,
                                               float* __restrict__ out) {
  __shared__ float lnv[512];
  __shared__ float sred[16];
  __shared__ float pred[4][128];
  int bx = blockIdx.x;
  int db = bx & 3, b = bx >> 2;
  int t = threadIdx.x;
  float f = fused[b * 512 + t] * (1.0f / 12294.0f);
  float s1 = f, s2 = f * f;
  for (int off = 1; off < 64; off <<= 1) {
    s1 += __shfl_xor(s1, off);
    s2 += __shfl_xor(s2, off);
  }
  if ((t & 63) == 0) {
    sred[(t >> 6) * 2] = s1;
    sred[(t >> 6) * 2 + 1] = s2;
  }
  __syncthreads();
  float S1 = 0.f, S2 = 0.f;
  for (int ww = 0; ww < 8; ++ww) {
    S1 += sred[ww * 2];
    S2 += sred[ww * 2 + 1];
  }
  float mu = S1 * (1.0f / 512.0f);
  float var = S2 * (1.0f / 512.0f) - mu * mu;
  float rstd = rsqrtf(var + 1e-5f);
  lnv[t] = (f - mu) * rstd * gamma[t] + beta[t];
  __syncthreads();
  int dt = t & 127, eq = t >> 7;
  int d = db * 128 + dt;
  float acc = 0.f;
  for (int e = eq * 128; e < eq * 128 + 128; ++e)
    acc += lnv[e] * Wf[(size_t)e * 512 + d];
  pred[eq][dt] = acc;
  __syncthreads();
  if (t < 128) {
    float r = pred[0][t] + pred[1][t] + pred[2][t] + pred[3][t] + bfv[db * 128 + t];
    out[b * 512 + db * 128 + t] = r;
  }
}

extern "C" void kernel_launch(void* const* d_in, const int* in_sizes, int n_in,
                              void* d_out, int out_size, void* d_ws, size_t ws_size,
                              hipStream_t stream) {
  const float* e0 = (const float*)d_in[0];
  const float* e1 = (const float*)d_in[1];
  const float* e2 = (const float*)d_in[2];
  const float* W1 = (const float*)d_in[3];
  const float* b1 = (const float*)d_in[4];
  const float* W2 = (const float*)d_in[5];
  // d_in[6] = b2: exactly cancelled by softmax shift invariance
  const float* gamma = (const float*)d_in[7];
  const float* beta = (const float*)d_in[8];
  const float* Wf = (const float*)d_in[9];
  const float* bf = (const float*)d_in[10];

  // workspace layout, smallest-first; packA sized by batch group nb
  char* ws = (char*)d_ws;
  float* fused = (float*)ws;                    // 16384 B
  float* logits = (float*)(ws + 16384);         // 786432 B
  u16* W1p = (u16*)(ws + 802816);               // 3145728 B
  u16* packA = (u16*)(ws + 3948544);            // nb * 12582912 B
  int nbat = 8;
  while (nbat > 1 && 3948544 + (size_t)nbat * 12582912 > ws_size) nbat >>= 1;

  hipLaunchKernelGGL(k_zero, dim3(16), dim3(256), 0, stream, fused, 4096);
  hipLaunchKernelGGL(k_packW, dim3(3072), dim3(64), 0, stream, W1, W1p);
  for (int b0 = 0; b0 < 8; b0 += nbat) {
    hipLaunchKernelGGL(k_poolpack, dim3(3 * nbat * 128), dim3(512), 0, stream,
                       e0, e1, e2, packA, b0, nbat);
    hipLaunchKernelGGL(k_gemm, dim3(6 * nbat * 64), dim3(512), 0, stream,
                       packA, W1p, b1, W2, logits, b0, nbat);
  }
  hipLaunchKernelGGL(k_softmax, dim3(48), dim3(256), 0, stream, logits);
  hipLaunchKernelGGL(k_matched, dim3(512), dim3(256), 0, stream, e0, e1, e2, logits, fused);
  hipLaunchKernelGGL(k_final, dim3(32), dim3(512), 0, stream, fused, gamma, beta, Wf, bf,
                     (float*)d_out);
}

// Round 7
// 537.911 us; speedup vs baseline: 1.0475x; 1.0475x over previous
//
#include <hip/hip_runtime.h>
#include <hip/hip_bf16.h>

typedef unsigned short u16;
typedef __bf16 bf16x8 __attribute__((ext_vector_type(8)));
typedef float f32x4 __attribute__((ext_vector_type(4)));

// B=8, S=4096 (spatial), C=512 (channels). per-batch embed elems = 2097152.
// packA (per batch-group): [nb][3 scales][sgb 256][cb 16][lane 64][e 8] bf16
//   fragment def: packA[lb][sc][sgb][cb][l][e] = pooled[c=cb*32+(l>>4)*8+e][s=sgb*16+(l&15)]

static __device__ __forceinline__ u16 f2bf(float f) {
  unsigned u = __builtin_bit_cast(unsigned, f);
  unsigned r = (u + 0x7FFFu + ((u >> 16) & 1u)) >> 16;
  return (u16)r;
}

// ---------------- fused 3x3x3 avg-pool (/27, count_include_pad) + A-pack ----
__global__ __launch_bounds__(512) void k_poolpack(const float* __restrict__ e0,
                                                  const float* __restrict__ e1,
                                                  const float* __restrict__ e2,
                                                  u16* __restrict__ packA,
                                                  int b0, int nb) {
  __shared__ __align__(16) float v[4096];
  __shared__ __align__(16) float t1[4096];
  __shared__ __align__(16) u16 outp[16384];   // [s][ci 0..3]
  int bx = blockIdx.x;
  int cg4 = bx & 127;
  int q = bx >> 7;
  int scale = q / nb;
  int lb = q - scale * nb;
  int b = b0 + lb;
  const float* eptr = scale == 0 ? e0 : (scale == 1 ? e1 : e2);
  const int LW = (scale == 0) ? 4 : (scale == 1 ? 3 : 4);
  const int LHW = (scale == 0) ? 8 : (scale == 1 ? 7 : 9);
  const int w = 1 << LW, hw = 1 << LHW;
  const int h = hw >> LW;
  const int dep = 4096 >> LHW;
  int t = threadIdx.x;
  int c0 = cg4 * 4;
  for (int ci = 0; ci < 4; ++ci) {
    const float* src = eptr + (size_t)b * 2097152 + (size_t)(c0 + ci) * 4096;
    ((float4*)v)[t] = ((const float4*)src)[t];
    ((float4*)v)[t + 512] = ((const float4*)src)[t + 512];
    __syncthreads();
    for (int j = 0; j < 8; ++j) {          // x pass
      int s = t + j * 512;
      int x = s & (w - 1);
      float sum = v[s];
      if (x > 0) sum += v[s - 1];
      if (x < w - 1) sum += v[s + 1];
      t1[s] = sum;
    }
    __syncthreads();
    for (int j = 0; j < 8; ++j) {          // y pass
      int s = t + j * 512;
      int y = (s >> LW) & (h - 1);
      float sum = t1[s];
      if (y > 0) sum += t1[s - w];
      if (y < h - 1) sum += t1[s + w];
      v[s] = sum;
    }
    __syncthreads();
    for (int j = 0; j < 8; ++j) {          // z pass -> bf16
      int s = t + j * 512;
      int z = s >> LHW;
      float sum = v[s];
      if (z > 0) sum += v[s - hw];
      if (z < dep - 1) sum += v[s + hw];
      outp[s * 4 + ci] = f2bf(sum * (1.0f / 27.0f));
    }
    __syncthreads();
  }
  int cb = c0 >> 5;
  int hi = (c0 >> 3) & 3;
  int eh = (c0 >> 2) & 1;
  size_t blk = (size_t)(lb * 3 + scale) * 2097152;
  for (int k2 = 0; k2 < 8; ++k2) {
    int s = t + k2 * 512;
    int2 val = *(const int2*)&outp[s * 4];
    size_t dst = blk + ((size_t)(s >> 4) * 16 + cb) * 512 +
                 (size_t)(hi * 16 + (s & 15)) * 8 + eh * 4;
    *(int2*)(packA + dst) = val;
  }
}

// ---------------- pack W1 into MFMA B-fragment layout -----------------------
// W1p[(kp*32+nb)*32+kb][l][e] = W1[kp][kb*32 + (l>>4)*8 + e][nb*16 + (l&15)]
__global__ __launch_bounds__(64) void k_packW(const float* __restrict__ W1,
                                              u16* __restrict__ W1p) {
  int u = blockIdx.x;
  int kb = u & 31;
  int nb_ = (u >> 5) & 31;
  int kp = u >> 10;
  int l = threadIdx.x;
  int m = l & 15, hi = l >> 4;
  u16 tmp[8];
  for (int e = 0; e < 8; ++e) {
    int kg = kb * 32 + hi * 8 + e;
    tmp[e] = f2bf(W1[((size_t)kp * 1024 + kg) * 512 + nb_ * 16 + m]);
  }
  *(int4*)(W1p + ((size_t)u * 64 + l) * 8) = *(int4*)tmp;
}

// ---------------- fused GEMM + bias + relu + dot(W2) -> partial logits ------
// m97-style: 256 threads (4 waves, 2x2), 128x128 output tile, A+B double-
// buffered in LDS via global_load_lds, counted vmcnt(4). Per K-step/wave:
// 16 MFMA : 8 ds_read_b128 : 4 glds. nt-partial W2-dots atomicAdd into logits.
__global__ __launch_bounds__(256, 3) void k_gemm(const u16* __restrict__ packA,
                                                 const u16* __restrict__ W1p,
                                                 const float* __restrict__ b1,
                                                 const float* __restrict__ W2,
                                                 float* __restrict__ logits,
                                                 int b0, int nb) {
  __shared__ __align__(16) u16 abuf[2][4096];  // 8 row-units x 64 lanes x 8
  __shared__ __align__(16) u16 bbuf[2][4096];  // 8 col-units x 64 lanes x 8
  __shared__ float red[2][128];
  int per = gridDim.x >> 3;                 // grid = 768*nb, always %8==0
  int logical = (blockIdx.x & 7) * per + (blockIdx.x >> 3);
  int nt = logical & 3;                     // N-tile (128 cols), fastest -> L2
  int mt = (logical >> 2) & 31;             // M-tile (128 rows)
  int rest = logical >> 7;                  // dir*nb + lb
  int lb = rest % nb;
  int dir = rest / nb;
  int b = b0 + lb;
  int kp = dir >> 1, sw = dir & 1;
  const int PI[3] = {0, 0, 1}, PJ[3] = {1, 2, 2};
  int pi = PI[kp], pj = PJ[kp];
  int first = sw ? pj : pi;
  int second = sw ? pi : pj;
  int t = threadIdx.x;
  int w = t >> 6;
  int l = t & 63;
  int wr = w & 1, wc = w >> 1;              // wave's 64-row / 64-col quadrant
  const u16* Abase1 = packA + (size_t)(lb * 3 + first) * 2097152;
  const u16* Abase2 = packA + (size_t)(lb * 3 + second) * 2097152;

  f32x4 acc[4][4];
  for (int a = 0; a < 4; ++a)
    for (int n = 0; n < 4; ++n) acc[a][n] = (f32x4){0.f, 0.f, 0.f, 0.f};

  // K-step T (0..31): panel = T<16 ? first : second, cb = T&15.
  // Each wave stages 2 A row-units + 2 B col-units (1 KiB each via glds-16B).
#define STAGE(BUFI, T)                                                            \
  do {                                                                            \
    const u16* P_ = ((T) < 16) ? Abase1 : Abase2;                                 \
    int cb_ = (T) & 15;                                                           \
    for (int r_ = 0; r_ < 2; ++r_) {                                              \
      int u_ = r_ * 4 + w;                                                        \
      const u16* g_ = P_ + ((size_t)((mt * 8 + u_) * 16 + cb_)) * 512 +           \
                      (size_t)l * 8;                                              \
      __builtin_amdgcn_global_load_lds(                                           \
          (const __attribute__((address_space(1))) void*)g_,                      \
          (__attribute__((address_space(3))) void*)&abuf[BUFI][u_ * 512],         \
          16, 0, 0);                                                              \
    }                                                                             \
    for (int r_ = 0; r_ < 2; ++r_) {                                              \
      int u_ = r_ * 4 + w;                                                        \
      const u16* g_ = W1p + ((size_t)((kp * 32 + nt * 8 + u_) * 32 + (T))) * 512 +\
                      (size_t)l * 8;                                              \
      __builtin_amdgcn_global_load_lds(                                           \
          (const __attribute__((address_space(1))) void*)g_,                      \
          (__attribute__((address_space(3))) void*)&bbuf[BUFI][u_ * 512],         \
          16, 0, 0);                                                              \
    }                                                                             \
  } while (0)

#define COMPUTE(BUFI)                                                             \
  do {                                                                            \
    bf16x8 af[4], bfr[4];                                                         \
    _Pragma("unroll")                                                             \
    for (int mi = 0; mi < 4; ++mi)                                                \
      af[mi] = *(const bf16x8*)&abuf[BUFI][(wr * 4 + mi) * 512 + l * 8];          \
    _Pragma("unroll")                                                             \
    for (int ni = 0; ni < 4; ++ni)                                                \
      bfr[ni] = *(const bf16x8*)&bbuf[BUFI][(wc * 4 + ni) * 512 + l * 8];         \
    _Pragma("unroll")                                                             \
    for (int mi = 0; mi < 4; ++mi)                                                \
      _Pragma("unroll")                                                           \
      for (int ni = 0; ni < 4; ++ni)                                              \
        acc[mi][ni] = __builtin_amdgcn_mfma_f32_16x16x32_bf16(                    \
            af[mi], bfr[ni], acc[mi][ni], 0, 0, 0);                               \
  } while (0)

  STAGE(0, 0);
  for (int tt = 0; tt < 31; ++tt) {
    STAGE((tt + 1) & 1, tt + 1);
    asm volatile("s_waitcnt vmcnt(4)" ::: "memory");  // prev chunk landed
    __builtin_amdgcn_sched_barrier(0);
    __builtin_amdgcn_s_barrier();
    COMPUTE(tt & 1);
    __builtin_amdgcn_s_barrier();
  }
  asm volatile("s_waitcnt vmcnt(0)" ::: "memory");
  __builtin_amdgcn_sched_barrier(0);
  __builtin_amdgcn_s_barrier();
  COMPUTE(1);
#undef STAGE
#undef COMPUTE

  int m = l & 15, hi = l >> 4;
  float w2v[4], b1v[4];
  for (int ni = 0; ni < 4; ++ni) {
    int n = nt * 128 + wc * 64 + ni * 16 + m;
    w2v[ni] = W2[kp * 512 + n];
    b1v[ni] = b1[kp * 512 + n];
  }
  for (int mi = 0; mi < 4; ++mi)
    for (int r = 0; r < 4; ++r) {
      float s = 0.f;
      for (int ni = 0; ni < 4; ++ni) {
        float h = acc[mi][ni][r] + b1v[ni];
        s += fmaxf(h, 0.f) * w2v[ni];
      }
      float vv = s;
      vv += __shfl_xor(vv, 1);
      vv += __shfl_xor(vv, 2);
      vv += __shfl_xor(vv, 4);
      vv += __shfl_xor(vv, 8);
      if (m == 0) red[wc][wr * 64 + mi * 16 + hi * 4 + r] = vv;
    }
  __syncthreads();
  if (t < 128) {
    float s = red[0][t] + red[1][t];
    atomicAdd(&logits[((size_t)dir * 8 + b) * 4096 + mt * 128 + t], s);
  }
}

// ---------------- softmax over N per (dir,b), in-place, NaN-scrubbing -------
__global__ __launch_bounds__(256) void k_softmax(float* __restrict__ logits) {
  __shared__ __align__(16) float buf[4096];
  __shared__ float wred[4];
  int row = blockIdx.x;
  float* p = logits + (size_t)row * 4096;
  int t = threadIdx.x;
  float lmax = -1e30f;
  for (int j = 0; j < 4; ++j) {
    float4 v = ((const float4*)p)[t + j * 256];
    v.x = fmaxf(fminf(v.x, 1e4f), -1e4f);
    v.y = fmaxf(fminf(v.y, 1e4f), -1e4f);
    v.z = fmaxf(fminf(v.z, 1e4f), -1e4f);
    v.w = fmaxf(fminf(v.w, 1e4f), -1e4f);
    ((float4*)buf)[t + j * 256] = v;
    lmax = fmaxf(lmax, fmaxf(fmaxf(v.x, v.y), fmaxf(v.z, v.w)));
  }
  for (int off = 1; off < 64; off <<= 1) lmax = fmaxf(lmax, __shfl_xor(lmax, off));
  if ((t & 63) == 0) wred[t >> 6] = lmax;
  __syncthreads();
  float gmax = fmaxf(fmaxf(wred[0], wred[1]), fmaxf(wred[2], wred[3]));
  __syncthreads();
  float lsum = 0.f;
  for (int j = 0; j < 16; ++j) {
    int s = t + j * 256;
    float ex = expf(buf[s] - gmax);
    buf[s] = ex;
    lsum += ex;
  }
  for (int off = 1; off < 64; off <<= 1) lsum += __shfl_xor(lsum, off);
  if ((t & 63) == 0) wred[t >> 6] = lsum;
  __syncthreads();
  float inv = 1.f / (wred[0] + wred[1] + wred[2] + wred[3]);
  for (int j = 0; j < 4; ++j) {
    int i4 = t + j * 256;
    float4 v = ((const float4*)buf)[i4];
    v.x *= inv; v.y *= inv; v.z *= inv; v.w *= inv;
    ((float4*)p)[i4] = v;
  }
}

__global__ void k_zero(float* __restrict__ p, int n) {
  int i = blockIdx.x * 256 + threadIdx.x;
  if (i < n) p[i] = 0.f;
}

// ---------------- weighted sums + embed sums -> fused accumulator -----------
__global__ __launch_bounds__(256) void k_matched(const float* __restrict__ e0,
                                                 const float* __restrict__ e1,
                                                 const float* __restrict__ e2,
                                                 const float* __restrict__ wts,
                                                 float* __restrict__ fused) {
  __shared__ float lw[384];
  int bx = blockIdx.x;
  int nc = bx & 63;
  int b = bx >> 6;
  int n0 = nc * 64;
  int t = threadIdx.x;
  for (int idx = t; idx < 384; idx += 256) {
    int dir = idx >> 6, nn = idx & 63;
    lw[idx] = wts[((size_t)dir * 8 + b) * 4096 + n0 + nn];
  }
  __syncthreads();
  size_t base = (size_t)b * 2097152 + (size_t)n0 * 512;
  const float2* p0 = (const float2*)(e0 + base) + t;
  const float2* p1 = (const float2*)(e1 + base) + t;
  const float2* p2 = (const float2*)(e2 + base) + t;
  float2 tot = {0.f, 0.f};
  float2 m0 = {0, 0}, m1 = {0, 0}, m2 = {0, 0}, m3 = {0, 0}, m4 = {0, 0}, m5 = {0, 0};
  for (int nn = 0; nn < 64; ++nn) {
    float2 v0 = p0[nn * 256];
    float2 v1 = p1[nn * 256];
    float2 v2 = p2[nn * 256];
    tot.x += v0.x + v1.x + v2.x;
    tot.y += v0.y + v1.y + v2.y;
    float w0 = lw[0 * 64 + nn], w1 = lw[1 * 64 + nn], w2 = lw[2 * 64 + nn];
    float w3 = lw[3 * 64 + nn], w4 = lw[4 * 64 + nn], w5 = lw[5 * 64 + nn];
    m0.x += w0 * v1.x; m0.y += w0 * v1.y;
    m1.x += w1 * v0.x; m1.y += w1 * v0.y;
    m2.x += w2 * v2.x; m2.y += w2 * v2.y;
    m3.x += w3 * v0.x; m3.y += w3 * v0.y;
    m4.x += w4 * v2.x; m4.y += w4 * v2.y;
    m5.x += w5 * v1.x; m5.y += w5 * v1.y;
  }
  float rx = tot.x + m0.x + m1.x + m2.x + m3.x + m4.x + m5.x;
  float ry = tot.y + m0.y + m1.y + m2.y + m3.y + m4.y + m5.y;
  atomicAdd(&fused[b * 512 + 2 * t], rx);
  atomicAdd(&fused[b * 512 + 2 * t + 1], ry);
}

// ---------------- mean-div, LN, final matmul --------------------------------
__global__ __launch_bounds__(512) void k_final(const float* __restrict__ fused,
                                               const float* __restrict__ gamma,
                                               const float* __restrict__ beta,
                                               const float* __restrict__ Wf,
                                               const float* __restrict__ bfv,
                                               float* __restrict__ out) {
  __shared__ float lnv[512];
  __shared__ float sred[16];
  __shared__ float pred[4][128];
  int bx = blockIdx.x;
  int db = bx & 3, b = bx >> 2;
  int t = threadIdx.x;
  float f = fused[b * 512 + t] * (1.0f / 12294.0f);
  float s1 = f, s2 = f * f;
  for (int off = 1; off < 64; off <<= 1) {
    s1 += __shfl_xor(s1, off);
    s2 += __shfl_xor(s2, off);
  }
  if ((t & 63) == 0) {
    sred[(t >> 6) * 2] = s1;
    sred[(t >> 6) * 2 + 1] = s2;
  }
  __syncthreads();
  float S1 = 0.f, S2 = 0.f;
  for (int ww = 0; ww < 8; ++ww) {
    S1 += sred[ww * 2];
    S2 += sred[ww * 2 + 1];
  }
  float mu = S1 * (1.0f / 512.0f);
  float var = S2 * (1.0f / 512.0f) - mu * mu;
  float rstd = rsqrtf(var + 1e-5f);
  lnv[t] = (f - mu) * rstd * gamma[t] + beta[t];
  __syncthreads();
  int dt = t & 127, eq = t >> 7;
  int d = db * 128 + dt;
  float acc = 0.f;
  for (int e = eq * 128; e < eq * 128 + 128; ++e)
    acc += lnv[e] * Wf[(size_t)e * 512 + d];
  pred[eq][dt] = acc;
  __syncthreads();
  if (t < 128) {
    float r = pred[0][t] + pred[1][t] + pred[2][t] + pred[3][t] + bfv[db * 128 + t];
    out[b * 512 + db * 128 + t] = r;
  }
}

extern "C" void kernel_launch(void* const* d_in, const int* in_sizes, int n_in,
                              void* d_out, int out_size, void* d_ws, size_t ws_size,
                              hipStream_t stream) {
  const float* e0 = (const float*)d_in[0];
  const float* e1 = (const float*)d_in[1];
  const float* e2 = (const float*)d_in[2];
  const float* W1 = (const float*)d_in[3];
  const float* b1 = (const float*)d_in[4];
  const float* W2 = (const float*)d_in[5];
  // d_in[6] = b2: exactly cancelled by softmax shift invariance
  const float* gamma = (const float*)d_in[7];
  const float* beta = (const float*)d_in[8];
  const float* Wf = (const float*)d_in[9];
  const float* bf = (const float*)d_in[10];

  // workspace layout, smallest-first; packA sized by batch group nb
  char* ws = (char*)d_ws;
  float* fused = (float*)ws;                    // 16384 B
  float* logits = (float*)(ws + 16384);         // 786432 B (contiguous w/ fused)
  u16* W1p = (u16*)(ws + 802816);               // 3145728 B
  u16* packA = (u16*)(ws + 3948544);            // nb * 12582912 B
  int nbat = 8;
  while (nbat > 1 && 3948544 + (size_t)nbat * 12582912 > ws_size) nbat >>= 1;

  // zero fused + logits together (contiguous 200704 floats); logits now
  // accumulated via atomicAdd of nt-partials.
  hipLaunchKernelGGL(k_zero, dim3(784), dim3(256), 0, stream, fused, 200704);
  hipLaunchKernelGGL(k_packW, dim3(3072), dim3(64), 0, stream, W1, W1p);
  for (int b0 = 0; b0 < 8; b0 += nbat) {
    hipLaunchKernelGGL(k_poolpack, dim3(3 * nbat * 128), dim3(512), 0, stream,
                       e0, e1, e2, packA, b0, nbat);
    hipLaunchKernelGGL(k_gemm, dim3(768 * nbat), dim3(256), 0, stream,
                       packA, W1p, b1, W2, logits, b0, nbat);
  }
  hipLaunchKernelGGL(k_softmax, dim3(48), dim3(256), 0, stream, logits);
  hipLaunchKernelGGL(k_matched, dim3(512), dim3(256), 0, stream, e0, e1, e2, logits, fused);
  hipLaunchKernelGGL(k_final, dim3(32), dim3(512), 0, stream, fused, gamma, beta, Wf, bf,
                     (float*)d_out);
}